// Round 3
// baseline (161.647 us; speedup 1.0000x reference)
//
#include <hip/hip_runtime.h>

// B=32, N=2048, FE=32, T=12, OUT=3
#define FE_ 32
#define T_  12
#define M_  (32 * 2048)
#define SEQ 16                 // sequences per block
#define THREADS (SEQ * T_)     // 192 = 3 waves
#define XSTR 392               // 384 floats/seq + 8 pad (bank-conflict break)
#define GSTR 37                // 36 gate floats + 1 pad

// Phase 0: block stages 16 contiguous sequences (96 KB/4 = 24 KB) of x into
// LDS via perfectly coalesced float4 loads (8 per thread).
// Phase 1: thread (s,t) accumulates the 3 gate pre-activations from LDS.
// Phase 2: lanes 0..15 run the 12-step recurrence + 3-wide output GEMV.
__global__ __launch_bounds__(THREADS) void gru_fused_kernel(
    const float* __restrict__ x,      // (M, FE, T)
    const float* __restrict__ w_ih,   // (3, FE)
    const float* __restrict__ w_hh,   // (3, 1)
    const float* __restrict__ b_ih,   // (3,)
    const float* __restrict__ b_hh,   // (3,)
    const float* __restrict__ lin_w,  // (3, T)
    const float* __restrict__ lin_b,  // (3,)
    float* __restrict__ out)          // (M, 3)
{
    __shared__ float xs[SEQ * XSTR];    // 25088 B
    __shared__ float gbuf[SEQ * GSTR];  //  2368 B

    const int tid = threadIdx.x;
    const int m0  = blockIdx.x * SEQ;

    // ---- phase 0: coalesced global -> LDS (padded per-sequence rows) ----
    // block chunk = 16 seq * 384 floats = 1536 float4; 8 iters * 192 threads.
    const float4* __restrict__ xg = (const float4*)(x + (size_t)m0 * (FE_ * T_));
    const int sl = tid / 96;              // float4 (i*192+tid): seq = i*2 + tid/96
    const int rl = (tid - sl * 96) * 4;   // float offset within sequence
#pragma unroll
    for (int i = 0; i < 8; ++i) {
        const float4 v = xg[i * THREADS + tid];
        *(float4*)&xs[(i * 2 + sl) * XSTR + rl] = v;
    }
    __syncthreads();

    // ---- phase 1: gate pre-activations for (seq m0+s, step t) ----
    const int s = tid / T_;
    const int t = tid - s * T_;
    float a0 = b_ih[0], a1 = b_ih[1], a2 = b_ih[2];
    const float* __restrict__ xr = &xs[s * XSTR + t];
#pragma unroll
    for (int f = 0; f < FE_; ++f) {
        const float xv = xr[f * T_];            // bank (8s+12f+t)%32: <=3-way
        a0 = fmaf(xv, w_ih[0 * FE_ + f], a0);   // wave-uniform weight reads
        a1 = fmaf(xv, w_ih[1 * FE_ + f], a1);
        a2 = fmaf(xv, w_ih[2 * FE_ + f], a2);
    }
    float* g = &gbuf[s * GSTR + t * 3];
    g[0] = a0; g[1] = a1; g[2] = a2;
    __syncthreads();

    // ---- phase 2: recurrence + output head, one lane per sequence ----
    if (tid < SEQ) {
        const float wh0 = w_hh[0], wh1 = w_hh[1], wh2 = w_hh[2];
        const float bh0 = b_hh[0], bh1 = b_hh[1], bh2 = b_hh[2];
        float o0 = lin_b[0], o1 = lin_b[1], o2 = lin_b[2];
        const float* __restrict__ gg = &gbuf[tid * GSTR];
        float h = 0.0f;
#pragma unroll
        for (int tt = 0; tt < T_; ++tt) {
            const float r = 1.0f / (1.0f + __expf(-(gg[tt * 3 + 0] + wh0 * h + bh0)));
            const float z = 1.0f / (1.0f + __expf(-(gg[tt * 3 + 1] + wh1 * h + bh1)));
            const float y = gg[tt * 3 + 2] + r * (wh2 * h + bh2);
            const float n = 1.0f - 2.0f / (1.0f + __expf(2.0f * y));  // tanh(y)
            h = (1.0f - z) * n + z * h;
            const float ht = h > 0.0f ? h : 0.0f;                      // relu
            o0 = fmaf(ht, lin_w[0 * T_ + tt], o0);
            o1 = fmaf(ht, lin_w[1 * T_ + tt], o1);
            o2 = fmaf(ht, lin_w[2 * T_ + tt], o2);
        }
        float* __restrict__ po = out + (size_t)(m0 + tid) * 3;
        po[0] = o0; po[1] = o1; po[2] = o2;
    }
}

extern "C" void kernel_launch(void* const* d_in, const int* in_sizes, int n_in,
                              void* d_out, int out_size, void* d_ws, size_t ws_size,
                              hipStream_t stream) {
    (void)in_sizes; (void)n_in; (void)d_ws; (void)ws_size; (void)out_size;
    const float* x     = (const float*)d_in[0];
    const float* w_ih  = (const float*)d_in[1];
    const float* w_hh  = (const float*)d_in[2];
    const float* b_ih  = (const float*)d_in[3];
    const float* b_hh  = (const float*)d_in[4];
    const float* lin_w = (const float*)d_in[5];
    const float* lin_b = (const float*)d_in[6];
    float* out = (float*)d_out;

    const int grid = M_ / SEQ;   // 4096 blocks
    gru_fused_kernel<<<grid, THREADS, 0, stream>>>(x, w_ih, w_hh, b_ih, b_hh,
                                                   lin_w, lin_b, out);
}

// Round 4
// 161.332 us; speedup vs baseline: 1.0020x; 1.0020x over previous
//
#include <hip/hip_runtime.h>

// B=32, N=2048, FE=32, T=12, OUT=3
#define FE_ 32
#define T_  12
#define M_  (32 * 2048)
#define SEQB 64                 // sequences per block
#define THREADS (SEQB * 3)      // 192 = 3 waves; thread = (s, c), c = float4 col
#define GSTR 37                 // 36 gate floats + 1 pad per sequence

// Thread (s,c) streams 32 float4 (one per f, stride 48B, immediate offsets)
// directly into registers and accumulates the 3 gate pre-activations for
// t in [4c, 4c+4). No LDS round-trip for x; only the 36-float gate vector
// per sequence goes through LDS. Lanes 0..63 then run the recurrence.
__global__ __launch_bounds__(THREADS) void gru_fused_kernel(
    const float* __restrict__ x,      // (M, FE, T)
    const float* __restrict__ w_ih,   // (3, FE)
    const float* __restrict__ w_hh,   // (3, 1)
    const float* __restrict__ b_ih,   // (3,)
    const float* __restrict__ b_hh,   // (3,)
    const float* __restrict__ lin_w,  // (3, T)
    const float* __restrict__ lin_b,  // (3,)
    float* __restrict__ out)          // (M, 3)
{
    __shared__ float gbuf[SEQB * GSTR];   // 9472 B

    const int tid = threadIdx.x;
    const int s   = tid / 3;              // local sequence 0..63
    const int c   = tid - s * 3;          // float4 column 0..2 (t-range 4c..4c+3)
    const int m0  = blockIdx.x * SEQB;

    // ---- phase 1: gates[t][g] for t in [4c,4c+4), seq m0+s ----
    const float4* __restrict__ xq =
        (const float4*)x + (size_t)(m0 + s) * (FE_ * T_ / 4) + c;

    float a0x, a0y, a0z, a0w, a1x, a1y, a1z, a1w, a2x, a2y, a2z, a2w;
    const float bi0 = b_ih[0], bi1 = b_ih[1], bi2 = b_ih[2];
    a0x = a0y = a0z = a0w = bi0;
    a1x = a1y = a1z = a1w = bi1;
    a2x = a2y = a2z = a2w = bi2;

#pragma unroll
    for (int f = 0; f < FE_; ++f) {
        const float4 v = xq[f * 3];                 // dwordx4, imm offset f*48+c*16
        const float w0 = w_ih[0 * FE_ + f];         // wave-uniform -> s_load, hoisted
        const float w1 = w_ih[1 * FE_ + f];
        const float w2 = w_ih[2 * FE_ + f];
        a0x = fmaf(v.x, w0, a0x); a0y = fmaf(v.y, w0, a0y);
        a0z = fmaf(v.z, w0, a0z); a0w = fmaf(v.w, w0, a0w);
        a1x = fmaf(v.x, w1, a1x); a1y = fmaf(v.y, w1, a1y);
        a1z = fmaf(v.z, w1, a1z); a1w = fmaf(v.w, w1, a1w);
        a2x = fmaf(v.x, w2, a2x); a2y = fmaf(v.y, w2, a2y);
        a2z = fmaf(v.z, w2, a2z); a2w = fmaf(v.w, w2, a2w);
    }

    {
        float* g = &gbuf[s * GSTR + (c * 4) * 3];   // 12 floats for t=4c..4c+3
        g[0]  = a0x; g[1]  = a1x; g[2]  = a2x;
        g[3]  = a0y; g[4]  = a1y; g[5]  = a2y;
        g[6]  = a0z; g[7]  = a1z; g[8]  = a2z;
        g[9]  = a0w; g[10] = a1w; g[11] = a2w;
    }
    __syncthreads();

    // ---- phase 2: recurrence + output head, lanes 0..63 (wave 0) ----
    if (tid < SEQB) {
        const float wh0 = w_hh[0], wh1 = w_hh[1], wh2 = w_hh[2];
        const float bh0 = b_hh[0], bh1 = b_hh[1], bh2 = b_hh[2];
        float o0 = lin_b[0], o1 = lin_b[1], o2 = lin_b[2];
        const float* __restrict__ gg = &gbuf[tid * GSTR];  // stride 37: odd
        float h = 0.0f;
#pragma unroll
        for (int tt = 0; tt < T_; ++tt) {
            const float r = 1.0f / (1.0f + __expf(-(gg[tt * 3 + 0] + wh0 * h + bh0)));
            const float z = 1.0f / (1.0f + __expf(-(gg[tt * 3 + 1] + wh1 * h + bh1)));
            const float y = gg[tt * 3 + 2] + r * (wh2 * h + bh2);
            const float n = 1.0f - 2.0f / (1.0f + __expf(2.0f * y));   // tanh(y)
            h = (1.0f - z) * n + z * h;
            const float ht = h > 0.0f ? h : 0.0f;                       // relu
            o0 = fmaf(ht, lin_w[0 * T_ + tt], o0);
            o1 = fmaf(ht, lin_w[1 * T_ + tt], o1);
            o2 = fmaf(ht, lin_w[2 * T_ + tt], o2);
        }
        float* __restrict__ po = out + (size_t)(m0 + tid) * 3;
        po[0] = o0; po[1] = o1; po[2] = o2;   // 64 lanes x 12 B contiguous
    }
}

extern "C" void kernel_launch(void* const* d_in, const int* in_sizes, int n_in,
                              void* d_out, int out_size, void* d_ws, size_t ws_size,
                              hipStream_t stream) {
    (void)in_sizes; (void)n_in; (void)d_ws; (void)ws_size; (void)out_size;
    const float* x     = (const float*)d_in[0];
    const float* w_ih  = (const float*)d_in[1];
    const float* w_hh  = (const float*)d_in[2];
    const float* b_ih  = (const float*)d_in[3];
    const float* b_hh  = (const float*)d_in[4];
    const float* lin_w = (const float*)d_in[5];
    const float* lin_b = (const float*)d_in[6];
    float* out = (float*)d_out;

    const int grid = M_ / SEQB;   // 1024 blocks
    gru_fused_kernel<<<grid, THREADS, 0, stream>>>(x, w_ih, w_hh, b_ih, b_hh,
                                                   lin_w, lin_b, out);
}